// Round 15
// baseline (125.922 us; speedup 1.0000x reference)
//
#include <hip/hip_runtime.h>
#include <math.h>

static constexpr int BLK = 256;
static constexpr int R = 8;      // queries per thread
static constexpr int TILE = 128; // scan points per block (j-range; no LDS staging)
static constexpr float BIGW = 1e30f;  // finite sentinel

__device__ __forceinline__ unsigned f2u(float f) { return __float_as_uint(f); }
__device__ __forceinline__ float u2f(unsigned u) { return __uint_as_float(u); }

// prep: pack (x,y,z,0.5|p|^2) float4 arrays + sentinels + out=0. (~928 KB ws)
__global__ void prep_kernel(const float* __restrict__ P, const float* __restrict__ Ps,
                            float4* __restrict__ pp, float4* __restrict__ psp,
                            unsigned long long* __restrict__ o2s, unsigned* __restrict__ s2o,
                            float* __restrict__ out, int N, int M) {
    int i = blockIdx.x * blockDim.x + threadIdx.x;
    if (i < N) {
        float x = P[3 * i], y = P[3 * i + 1], z = P[3 * i + 2];
        pp[i] = make_float4(x, y, z, 0.5f * (x * x + y * y + z * z));
        o2s[i] = ~0ull;
    }
    if (i < M) {
        float x = Ps[3 * i], y = Ps[3 * i + 1], z = Ps[3 * i + 2];
        psp[i] = make_float4(x, y, z, 0.5f * (x * x + y * y + z * z));
        s2o[i] = 0xFFFFFFFFu;
    }
    if (i == 0) out[0] = 0.0f;
}

// Fused bidirectional NN scan — scan points via WAVE-UNIFORM loads (-> s_load,
// scalar pipe, constant cache), queries via coalesced float4 loads. NO LDS in
// the K-loop, no __syncthreads. Rationale (R14 post-mortem): the allocator
// pins arch-VGPRs at 32 and splits the r-loop, doubling ds_read traffic; LDS
// pipe ~41us was the floor of every LDS variant (R3..R14: 52-58us). Scalar
// loads make the split harmless and empty the LDS pipe entirely.
// min over d2 == min over m = 0.5|scan|^2 - qry.scan ; d2 = 2*(0.5|qry|^2 + m)
__global__ void __launch_bounds__(BLK) main_kernel(
    const float4* __restrict__ pp, const float4* __restrict__ psp,
    unsigned long long* __restrict__ o2s, unsigned* __restrict__ s2o,
    int N, int M, int o2sX, int o2sBlocks, int s2oX) {
    int bx = blockIdx.x;

    if (bx < o2sBlocks) {
        // ---- original -> sampled: queries = pp (N), scan = psp (M), min+argmin ----
        int ix = bx % o2sX, iy = bx / o2sX;
        int ibase = ix * (BLK * R) + threadIdx.x;
        int j0 = iy * TILE;  // uniform
        float px[R], py[R], pz[R], mmin[R];
#pragma unroll
        for (int r = 0; r < R; ++r) {
            int i = ibase + r * BLK;
            float4 t = (i < N) ? pp[i] : make_float4(0.f, 0.f, 0.f, 0.f);
            px[r] = -t.x; py[r] = -t.y; pz[r] = -t.z;
            mmin[r] = __builtin_inff();
        }
        const float4* base = psp + j0;  // uniform pointer
#pragma unroll 8
        for (int ii = 0; ii < TILE; ++ii) {
            float4 q = base[ii];  // uniform address -> s_load_dwordx4 (merges x16)
#pragma unroll
            for (int r = 0; r < R; ++r) {
                float m = fmaf(q.x, px[r], fmaf(q.y, py[r], fmaf(q.z, pz[r], q.w)));
                float mp = u2f((f2u(m) & 0xFFFFFF00u) | (unsigned)ii);
                mmin[r] = fminf(mmin[r], mp);
            }
        }
#pragma unroll
        for (int r = 0; r < R; ++r) {
            int i = ibase + r * BLK;
            if (i < N) {
                float pw = 0.5f * (px[r] * px[r] + py[r] * py[r] + pz[r] * pz[r]);
                unsigned j = (unsigned)j0 + (f2u(mmin[r]) & 0xFFu);
                float d2 = fmaxf(2.0f * (pw + mmin[r]), 0.0f);
                atomicMin(&o2s[i], ((unsigned long long)f2u(d2) << 32) | j);
            }
        }
    } else {
        // ---- sampled -> original: queries = psp (M), scan = pp (N), min only ----
        int b = bx - o2sBlocks;
        int ix = b % s2oX, iy = b / s2oX;
        int jbase = ix * (BLK * R) + threadIdx.x;
        int i0 = iy * TILE;  // uniform
        float qx[R], qy[R], qz[R], mmin[R];
#pragma unroll
        for (int r = 0; r < R; ++r) {
            int j = jbase + r * BLK;
            float4 t = (j < M) ? psp[j] : make_float4(0.f, 0.f, 0.f, 0.f);
            qx[r] = -t.x; qy[r] = -t.y; qz[r] = -t.z;
            mmin[r] = __builtin_inff();
        }
        const float4* base = pp + i0;  // uniform pointer
#pragma unroll 8
        for (int ii = 0; ii < TILE; ++ii) {
            float4 pt = base[ii];  // uniform address -> s_load_dwordx4
#pragma unroll
            for (int r = 0; r < R; ++r) {
                float m = fmaf(pt.x, qx[r], fmaf(pt.y, qy[r], fmaf(pt.z, qz[r], pt.w)));
                mmin[r] = fminf(mmin[r], m);
            }
        }
#pragma unroll
        for (int r = 0; r < R; ++r) {
            int j = jbase + r * BLK;
            if (j < M) {
                float qw = 0.5f * (qx[r] * qx[r] + qy[r] * qy[r] + qz[r] * qz[r]);
                float d2 = fmaxf(2.0f * (qw + mmin[r]), 0.0f);
                atomicMin(&s2o[j], f2u(d2));
            }
        }
    }
}

// finish: one load per query, weight, block-reduce, one atomicAdd per block.
__global__ void finish_kernel(const unsigned* __restrict__ s2o,
                              const unsigned long long* __restrict__ o2s,
                              const float* __restrict__ prob,
                              float* __restrict__ out, int N, int M) {
    int t = blockIdx.x * BLK + threadIdx.x;
    float acc = 0.0f;
    if (t < M) {
        acc = sqrtf(u2f(s2o[t])) * prob[t];
    } else if (t < M + N) {
        unsigned long long key = o2s[t - M];
        float d2 = u2f((unsigned)(key >> 32));
        unsigned jj = (unsigned)(key & 0xFFFFFFFFu);
        acc = sqrtf(d2) * prob[jj];
    }
#pragma unroll
    for (int off = 32; off > 0; off >>= 1) acc += __shfl_down(acc, off, 64);
    __shared__ float wsum[BLK / 64];
    int lane = threadIdx.x & 63, wave = threadIdx.x >> 6;
    if (lane == 0) wsum[wave] = acc;
    __syncthreads();
    if (threadIdx.x == 0) {
        float s = 0.0f;
#pragma unroll
        for (int w = 0; w < BLK / 64; ++w) s += wsum[w];
        atomicAdd(out, s);
    }
}

extern "C" void kernel_launch(void* const* d_in, const int* in_sizes, int n_in,
                              void* d_out, int out_size, void* d_ws, size_t ws_size,
                              hipStream_t stream) {
    const float* P = (const float*)d_in[0];
    const float* Ps = (const float*)d_in[1];
    const float* prob = (const float*)d_in[2];
    int N = in_sizes[0] / 3;  // 32768
    int M = in_sizes[1] / 3;  // 8192
    float* out = (float*)d_out;

    char* ws = (char*)d_ws;
    float4* pp = (float4*)ws;                                        // N*16
    float4* psp = (float4*)(ws + (size_t)N * 16);                    // M*16
    unsigned long long* o2s =
        (unsigned long long*)(ws + (size_t)(N + M) * 16);            // N*8
    unsigned* s2o =
        (unsigned*)(ws + (size_t)(N + M) * 16 + (size_t)N * 8);      // M*4

    int o2sX = (N + BLK * R - 1) / (BLK * R);   // 16
    int o2sY = (M + TILE - 1) / TILE;           // 64
    int s2oX = (M + BLK * R - 1) / (BLK * R);   // 4
    int s2oY = (N + TILE - 1) / TILE;           // 256
    int o2sBlocks = o2sX * o2sY;                // 1024
    int total = o2sBlocks + s2oX * s2oY;        // 2048 = 8 blocks/CU

    prep_kernel<<<(max(N, M) + BLK - 1) / BLK, BLK, 0, stream>>>(P, Ps, pp, psp,
                                                                 o2s, s2o, out, N, M);
    main_kernel<<<total, BLK, 0, stream>>>(pp, psp, o2s, s2o, N, M,
                                           o2sX, o2sBlocks, s2oX);
    finish_kernel<<<(N + M + BLK - 1) / BLK, BLK, 0, stream>>>(s2o, o2s, prob,
                                                               out, N, M);
}

// Round 16
// 106.209 us; speedup vs baseline: 1.1856x; 1.1856x over previous
//
#include <hip/hip_runtime.h>
#include <math.h>

static constexpr int BLK = 256;
static constexpr int R = 8;      // queries per thread
static constexpr int TILE = 128; // scan points per LDS tile (grid = 2048 blocks)
static constexpr float BIGW = 1e30f;  // finite sentinel

__device__ __forceinline__ unsigned f2u(float f) { return __float_as_uint(f); }
__device__ __forceinline__ float u2f(unsigned u) { return __uint_as_float(u); }

// prep: sentinels + out=0 (288 KB ws).
__global__ void prep_kernel(unsigned long long* __restrict__ o2s,
                            unsigned* __restrict__ s2o,
                            float* __restrict__ out, int N, int M) {
    int i = blockIdx.x * blockDim.x + threadIdx.x;
    if (i < N) o2s[i] = ~0ull;
    if (i < M) s2o[i] = 0xFFFFFFFFu;
    if (i == 0) out[0] = 0.0f;
}

// Fused bidirectional NN scan (R14 structure — best so far at 52.6us main).
// min over d2 == min over m = 0.5|scan|^2 - qry.scan ; d2 = 2*(0.5|qry|^2 + m)
// R15 post-mortem: VGPR_Count=32 cannot hold the 40+ live values -> compiler
// parks px/py/pz/mmin in AGPRs (unified file) and pays a v_accvgpr_read per
// inner-loop use: ~8 dynamic inst/pair instead of 5, = measured 52.6us.
// amdgpu_waves_per_eu(4,4) pins occupancy at 4 waves/EU -> VGPR budget 128,
// removing the allocator's reason to park anything in AGPRs. launch_bounds
// minimums alone (R9/R14) did NOT do this — allocator still chose 32.
__global__ void __launch_bounds__(BLK)
__attribute__((amdgpu_waves_per_eu(4, 4))) main_kernel(
    const float* __restrict__ P, const float* __restrict__ Ps,
    unsigned long long* __restrict__ o2s, unsigned* __restrict__ s2o,
    int N, int M, int o2sX, int o2sBlocks, int s2oX) {
    __shared__ float4 tile[TILE];
    int bx = blockIdx.x;

    if (bx < o2sBlocks) {
        // ---- original -> sampled: queries = P (N), scan = Ps (M), min+argmin ----
        int ix = bx % o2sX, iy = bx / o2sX;
        int ibase = ix * (BLK * R) + threadIdx.x;
        int j0 = iy * TILE;
        float px[R], py[R], pz[R], mmin[R];
#pragma unroll
        for (int r = 0; r < R; ++r) {
            int i = ibase + r * BLK;
            float x = 0.f, y = 0.f, z = 0.f;
            if (i < N) { x = P[3 * i]; y = P[3 * i + 1]; z = P[3 * i + 2]; }
            px[r] = -x; py[r] = -y; pz[r] = -z;
            mmin[r] = __builtin_inff();
        }
        if (threadIdx.x < TILE) {
            int idx = j0 + threadIdx.x;
            float x = 0.f, y = 0.f, z = 0.f, w = BIGW;
            if (idx < M) {
                x = Ps[3 * idx]; y = Ps[3 * idx + 1]; z = Ps[3 * idx + 2];
                w = 0.5f * (x * x + y * y + z * z);
            }
            tile[threadIdx.x] = make_float4(x, y, z, w);
        }
        __syncthreads();
#pragma unroll 4
        for (int ii = 0; ii < TILE; ++ii) {
            float4 q = tile[ii];
#pragma unroll
            for (int r = 0; r < R; ++r) {
                float m = fmaf(q.x, px[r], fmaf(q.y, py[r], fmaf(q.z, pz[r], q.w)));
                float mp = u2f((f2u(m) & 0xFFFFFF00u) | (unsigned)ii);
                mmin[r] = fminf(mmin[r], mp);
            }
        }
#pragma unroll
        for (int r = 0; r < R; ++r) {
            int i = ibase + r * BLK;
            if (i < N) {
                float pw = 0.5f * (px[r] * px[r] + py[r] * py[r] + pz[r] * pz[r]);
                unsigned j = (unsigned)j0 + (f2u(mmin[r]) & 0xFFu);
                float d2 = fmaxf(2.0f * (pw + mmin[r]), 0.0f);
                atomicMin(&o2s[i], ((unsigned long long)f2u(d2) << 32) | j);
            }
        }
    } else {
        // ---- sampled -> original: queries = Ps (M), scan = P (N), min only ----
        int b = bx - o2sBlocks;
        int ix = b % s2oX, iy = b / s2oX;
        int jbase = ix * (BLK * R) + threadIdx.x;
        int i0 = iy * TILE;
        float qx[R], qy[R], qz[R], mmin[R];
#pragma unroll
        for (int r = 0; r < R; ++r) {
            int j = jbase + r * BLK;
            float x = 0.f, y = 0.f, z = 0.f;
            if (j < M) { x = Ps[3 * j]; y = Ps[3 * j + 1]; z = Ps[3 * j + 2]; }
            qx[r] = -x; qy[r] = -y; qz[r] = -z;
            mmin[r] = __builtin_inff();
        }
        if (threadIdx.x < TILE) {
            int idx = i0 + threadIdx.x;
            float x = 0.f, y = 0.f, z = 0.f, w = BIGW;
            if (idx < N) {
                x = P[3 * idx]; y = P[3 * idx + 1]; z = P[3 * idx + 2];
                w = 0.5f * (x * x + y * y + z * z);
            }
            tile[threadIdx.x] = make_float4(x, y, z, w);
        }
        __syncthreads();
#pragma unroll 4
        for (int ii = 0; ii < TILE; ++ii) {
            float4 pt = tile[ii];
#pragma unroll
            for (int r = 0; r < R; ++r) {
                float m = fmaf(pt.x, qx[r], fmaf(pt.y, qy[r], fmaf(pt.z, qz[r], pt.w)));
                mmin[r] = fminf(mmin[r], m);
            }
        }
#pragma unroll
        for (int r = 0; r < R; ++r) {
            int j = jbase + r * BLK;
            if (j < M) {
                float qw = 0.5f * (qx[r] * qx[r] + qy[r] * qy[r] + qz[r] * qz[r]);
                float d2 = fmaxf(2.0f * (qw + mmin[r]), 0.0f);
                atomicMin(&s2o[j], f2u(d2));
            }
        }
    }
}

// finish: one load per query, weight, block-reduce, one atomicAdd per block.
__global__ void finish_kernel(const unsigned* __restrict__ s2o,
                              const unsigned long long* __restrict__ o2s,
                              const float* __restrict__ prob,
                              float* __restrict__ out, int N, int M) {
    int t = blockIdx.x * BLK + threadIdx.x;
    float acc = 0.0f;
    if (t < M) {
        acc = sqrtf(u2f(s2o[t])) * prob[t];
    } else if (t < M + N) {
        unsigned long long key = o2s[t - M];
        float d2 = u2f((unsigned)(key >> 32));
        unsigned jj = (unsigned)(key & 0xFFFFFFFFu);
        acc = sqrtf(d2) * prob[jj];
    }
#pragma unroll
    for (int off = 32; off > 0; off >>= 1) acc += __shfl_down(acc, off, 64);
    __shared__ float wsum[BLK / 64];
    int lane = threadIdx.x & 63, wave = threadIdx.x >> 6;
    if (lane == 0) wsum[wave] = acc;
    __syncthreads();
    if (threadIdx.x == 0) {
        float s = 0.0f;
#pragma unroll
        for (int w = 0; w < BLK / 64; ++w) s += wsum[w];
        atomicAdd(out, s);
    }
}

extern "C" void kernel_launch(void* const* d_in, const int* in_sizes, int n_in,
                              void* d_out, int out_size, void* d_ws, size_t ws_size,
                              hipStream_t stream) {
    const float* P = (const float*)d_in[0];
    const float* Ps = (const float*)d_in[1];
    const float* prob = (const float*)d_in[2];
    int N = in_sizes[0] / 3;  // 32768
    int M = in_sizes[1] / 3;  // 8192
    float* out = (float*)d_out;

    unsigned long long* o2s = (unsigned long long*)d_ws;       // N * 8 B
    unsigned* s2o = (unsigned*)((char*)d_ws + (size_t)N * 8);  // M * 4 B

    int o2sX = (N + BLK * R - 1) / (BLK * R);   // 16
    int o2sY = (M + TILE - 1) / TILE;           // 64
    int s2oX = (M + BLK * R - 1) / (BLK * R);   // 4
    int s2oY = (N + TILE - 1) / TILE;           // 256
    int o2sBlocks = o2sX * o2sY;                // 1024
    int total = o2sBlocks + s2oX * s2oY;        // 2048

    prep_kernel<<<(N + BLK - 1) / BLK, BLK, 0, stream>>>(o2s, s2o, out, N, M);
    main_kernel<<<total, BLK, 0, stream>>>(P, Ps, o2s, s2o, N, M,
                                           o2sX, o2sBlocks, s2oX);
    finish_kernel<<<(N + M + BLK - 1) / BLK, BLK, 0, stream>>>(s2o, o2s, prob,
                                                               out, N, M);
}